// Round 1
// baseline (197.731 us; speedup 1.0000x reference)
//
#include <hip/hip_runtime.h>
#include <math.h>

#define NB 32
#define NP 4096
#define NS 128
#define DI 512
#define DV 512
#define DP 768
#define NH 4
#define DC 1024
#define DH 256

// ---------------------------------------------------------------------------
// Kernel A: q[b,h,d] = dot(h_concat[b,:], qW[h,d,:]) + qb[h,d]
// grid = NB*NH blocks, 256 threads (one thread per d; DH == 256)
// ---------------------------------------------------------------------------
__global__ __launch_bounds__(256) void k_q(const float* __restrict__ h_int,
                                           const float* __restrict__ h_vc,
                                           const float* __restrict__ qW,
                                           const float* __restrict__ qb,
                                           float* __restrict__ q) {
    int b = blockIdx.x / NH, h = blockIdx.x % NH;
    __shared__ float hc[DC];
    int tid = threadIdx.x;
    for (int i = tid; i < DI; i += 256) hc[i] = h_int[b * DI + i];
    for (int i = tid; i < DV; i += 256) hc[DI + i] = h_vc[b * DV + i];
    __syncthreads();
    const float* w = qW + (size_t)(h * DH + tid) * DC;
    float acc = qb[h * DH + tid];
#pragma unroll 4
    for (int c = 0; c < DC; c += 4) {
        float4 wv = *(const float4*)(w + c);
        acc += wv.x * hc[c] + wv.y * hc[c + 1] + wv.z * hc[c + 2] + wv.w * hc[c + 3];
    }
    q[(size_t)(b * NH + h) * DH + tid] = acc;
}

// ---------------------------------------------------------------------------
// Kernel B: w_avg[b,c] = (1/H) * sum_{h,d} q[b,h,d] * kW[h,d,c]   [NB, DP]
//           bavg[b]   = (1/H) * sum_{h,d} q[b,h,d] * kb[h,d]
// grid = NB blocks, 256 threads (each thread owns c, c+256, c+512)
// ---------------------------------------------------------------------------
__global__ __launch_bounds__(256) void k_wavg(const float* __restrict__ q,
                                              const float* __restrict__ kW,
                                              const float* __restrict__ kb,
                                              float* __restrict__ w_avg,
                                              float* __restrict__ bavg) {
    int b = blockIdx.x;
    __shared__ float qs[NH * DH];  // 1024 floats
    int tid = threadIdx.x;
    for (int i = tid; i < NH * DH; i += 256) qs[i] = q[(size_t)b * NH * DH + i];
    __syncthreads();
    float a0 = 0.f, a1 = 0.f, a2 = 0.f;
    for (int i = 0; i < NH * DH; ++i) {
        float qv = qs[i];
        const float* kr = kW + (size_t)i * DP;
        a0 += qv * kr[tid];
        a1 += qv * kr[tid + 256];
        a2 += qv * kr[tid + 512];
    }
    const float inv_h = 1.0f / NH;
    w_avg[(size_t)b * DP + tid]       = a0 * inv_h;
    w_avg[(size_t)b * DP + tid + 256] = a1 * inv_h;
    w_avg[(size_t)b * DP + tid + 512] = a2 * inv_h;

    // bias: block reduction of qs[i]*kb[i]
    float pb = 0.f;
    for (int i = tid; i < NH * DH; i += 256) pb += qs[i] * kb[i];
    __shared__ float red[256];
    red[tid] = pb;
    __syncthreads();
    for (int s2 = 128; s2 > 0; s2 >>= 1) {
        if (tid < s2) red[tid] += red[tid + s2];
        __syncthreads();
    }
    if (tid == 0) bavg[b] = red[0] * inv_h;
}

// ---------------------------------------------------------------------------
// Kernel C (heavy): score[b,p] = patch[b,p,:]·w_avg[b,:] + bavg[b],
// run-accumulated into acc[b][seg] (seg via binary search over boundaries).
// One wave per patch-iteration; 3x coalesced float4 loads per lane.
// grid = NB*CHUNKS blocks, 256 threads (4 waves, each owns PPW patches)
// ---------------------------------------------------------------------------
__global__ __launch_bounds__(256) void k_score(const float* __restrict__ patch,
                                               const float* __restrict__ w_avg,
                                               const float* __restrict__ bavg,
                                               const int* __restrict__ bnd,
                                               float* __restrict__ acc) {
    constexpr int CHUNKS = 32;
    constexpr int PPB = NP / CHUNKS;  // 128 patches per block
    constexpr int PPW = PPB / 4;      // 32 patches per wave
    int b = blockIdx.x / CHUNKS;
    int chunk = blockIdx.x % CHUNKS;
    __shared__ int bsh[NS + 1];
    int tid = threadIdx.x;
    if (tid <= NS) bsh[tid] = bnd[tid];
    __syncthreads();
    int wave = tid >> 6, lane = tid & 63;

    // loop-invariant weights: 12 registers per lane
    const float4* w4 = (const float4*)(w_avg + (size_t)b * DP);
    float4 w0 = w4[lane], w1 = w4[64 + lane], w2 = w4[128 + lane];
    float bias = bavg[b];

    int p0 = chunk * PPB + wave * PPW;
    float run = 0.f;
    int cur = -1;  // current segment of the run (wave-uniform)
    for (int i = 0; i < PPW; ++i) {
        int p = p0 + i;
        const float4* r4 = (const float4*)(patch + ((size_t)b * NP + p) * DP);
        float4 v0 = r4[lane], v1 = r4[64 + lane], v2 = r4[128 + lane];
        float s = v0.x * w0.x + v0.y * w0.y + v0.z * w0.z + v0.w * w0.w
                + v1.x * w1.x + v1.y * w1.y + v1.z * w1.z + v1.w * w1.w
                + v2.x * w2.x + v2.y * w2.y + v2.z * w2.z + v2.w * w2.w;
#pragma unroll
        for (int off = 32; off > 0; off >>= 1) s += __shfl_xor(s, off);
        s += bias;  // uniform across the wave now

        // segment id: largest i in [0,NS] with bsh[i] <= p ; NS == dump bucket
        int seg;
        if (p < bsh[0]) {
            seg = NS;
        } else {
            int lo = 0, hi = NS;
            while (lo < hi) {
                int mid = (lo + hi + 1) >> 1;
                if (bsh[mid] <= p) lo = mid; else hi = mid - 1;
            }
            seg = lo;
        }
        if (seg != cur) {
            if (cur >= 0 && lane == 0) atomicAdd(&acc[b * (NS + 1) + cur], run);
            run = 0.f;
            cur = seg;
        }
        run += s;
    }
    if (cur >= 0 && lane == 0) atomicAdd(&acc[b * (NS + 1) + cur], run);
}

// ---------------------------------------------------------------------------
// Kernel D: out[b,s] = sigmoid(acc[b,s] / max(cnt[s],1)), cnt = bnd[s+1]-bnd[s]
// ---------------------------------------------------------------------------
__global__ __launch_bounds__(256) void k_out(const float* __restrict__ acc,
                                             const int* __restrict__ bnd,
                                             float* __restrict__ out) {
    int i = blockIdx.x * 256 + threadIdx.x;  // 0 .. NB*NS-1
    if (i >= NB * NS) return;
    int b = i / NS, s = i % NS;
    float cnt = (float)(bnd[s + 1] - bnd[s]);
    cnt = fmaxf(cnt, 1.0f);
    float v = acc[b * (NS + 1) + s] / cnt;
    out[i] = 1.0f / (1.0f + expf(-v));
}

extern "C" void kernel_launch(void* const* d_in, const int* in_sizes, int n_in,
                              void* d_out, int out_size, void* d_ws, size_t ws_size,
                              hipStream_t stream) {
    const float* h_int = (const float*)d_in[0];
    const float* h_vc  = (const float*)d_in[1];
    const float* patch = (const float*)d_in[2];
    const int*   bnd   = (const int*)d_in[3];
    const float* qW    = (const float*)d_in[4];
    const float* qb    = (const float*)d_in[5];
    const float* kW    = (const float*)d_in[6];
    const float* kb    = (const float*)d_in[7];
    float* out = (float*)d_out;

    char* ws = (char*)d_ws;
    float* acc   = (float*)ws;                               // NB*(NS+1) = 16.5 KB
    float* q     = (float*)(ws + 32 * 1024);                 // NB*NH*DH  = 128 KB
    float* w_avg = (float*)(ws + 32 * 1024 + 128 * 1024);    // NB*DP     = 96 KB
    float* bavg  = (float*)(ws + 32 * 1024 + 224 * 1024);    // NB floats

    hipMemsetAsync(acc, 0, NB * (NS + 1) * sizeof(float), stream);
    k_q<<<NB * NH, 256, 0, stream>>>(h_int, h_vc, qW, qb, q);
    k_wavg<<<NB, 256, 0, stream>>>(q, kW, kb, w_avg, bavg);
    k_score<<<NB * 32, 256, 0, stream>>>(patch, w_avg, bavg, bnd, acc);
    k_out<<<(NB * NS + 255) / 256, 256, 0, stream>>>(acc, bnd, out);
}

// Round 2
// 138.595 us; speedup vs baseline: 1.4267x; 1.4267x over previous
//
#include <hip/hip_runtime.h>
#include <math.h>

#define NB 32
#define NP 4096
#define NS 128
#define DI 512
#define DV 512
#define DP 768
#define NH 4
#define DC 1024
#define DH 256

// ---------------------------------------------------------------------------
// Kernel Z: zero the workspace accumulators (acc, w_avg, bavg)
// ---------------------------------------------------------------------------
__global__ __launch_bounds__(256) void k_zero(float* __restrict__ ws0, int n) {
    int i = blockIdx.x * 256 + threadIdx.x;
    if (i < n) ws0[i] = 0.f;
}

// ---------------------------------------------------------------------------
// Kernel A: q[b,h,d] = dot(h_concat[b,:], qW[h,d,:]) + qb[h,d]
// grid = NB*NH blocks, 256 threads (one thread per d; DH == 256)
// ---------------------------------------------------------------------------
__global__ __launch_bounds__(256) void k_q(const float* __restrict__ h_int,
                                           const float* __restrict__ h_vc,
                                           const float* __restrict__ qW,
                                           const float* __restrict__ qb,
                                           float* __restrict__ q) {
    int b = blockIdx.x / NH, h = blockIdx.x % NH;
    __shared__ float hc[DC];
    int tid = threadIdx.x;
    for (int i = tid; i < DI; i += 256) hc[i] = h_int[b * DI + i];
    for (int i = tid; i < DV; i += 256) hc[DI + i] = h_vc[b * DV + i];
    __syncthreads();
    const float* w = qW + (size_t)(h * DH + tid) * DC;
    float acc = qb[h * DH + tid];
#pragma unroll 4
    for (int c = 0; c < DC; c += 4) {
        float4 wv = *(const float4*)(w + c);
        acc += wv.x * hc[c] + wv.y * hc[c + 1] + wv.z * hc[c + 2] + wv.w * hc[c + 3];
    }
    q[(size_t)(b * NH + h) * DH + tid] = acc;
}

// ---------------------------------------------------------------------------
// Kernel B: w_avg[b,c] += (1/H) * sum_{i in kchunk} q[b,i] * kW[i,c]
//           bavg[b]    += (1/H) * sum_{i in kchunk} q[b,i] * kb[i]
// grid = NB*KSPLIT blocks, 256 threads (thread owns c, c+256, c+512)
// ---------------------------------------------------------------------------
constexpr int KSPLIT = 8;
__global__ __launch_bounds__(256) void k_wavg(const float* __restrict__ q,
                                              const float* __restrict__ kW,
                                              const float* __restrict__ kb,
                                              float* __restrict__ w_avg,
                                              float* __restrict__ bavg) {
    constexpr int IPC = NH * DH / KSPLIT;  // 128 rows per chunk
    int b = blockIdx.x / KSPLIT, ks = blockIdx.x % KSPLIT;
    __shared__ float qs[IPC];
    int tid = threadIdx.x;
    if (tid < IPC) qs[tid] = q[(size_t)b * NH * DH + ks * IPC + tid];
    __syncthreads();
    float a0 = 0.f, a1 = 0.f, a2 = 0.f;
    for (int i = 0; i < IPC; ++i) {
        float qv = qs[i];
        const float* kr = kW + (size_t)(ks * IPC + i) * DP;
        a0 += qv * kr[tid];
        a1 += qv * kr[tid + 256];
        a2 += qv * kr[tid + 512];
    }
    const float inv_h = 1.0f / NH;
    atomicAdd(&w_avg[(size_t)b * DP + tid],       a0 * inv_h);
    atomicAdd(&w_avg[(size_t)b * DP + tid + 256], a1 * inv_h);
    atomicAdd(&w_avg[(size_t)b * DP + tid + 512], a2 * inv_h);

    float pb = 0.f;
    if (tid < IPC) pb = qs[tid] * kb[ks * IPC + tid];
#pragma unroll
    for (int off = 32; off > 0; off >>= 1) pb += __shfl_xor(pb, off);
    if ((tid & 63) == 0) atomicAdd(&bavg[b], pb * inv_h);
}

// ---------------------------------------------------------------------------
// Kernel C (heavy, streaming): per segment-run, accumulate the VECTOR sum of
// patches in registers (12 FMAs/lane/patch); dot+reduce+atomic only at
// segment crossings (~1-2 per wave). Segment advances monotonically: one
// uniform compare per patch, no binary search in the loop.
// grid = NB*CHUNKS blocks, 256 threads (4 waves, each owns PPW patches)
// ---------------------------------------------------------------------------
__global__ __launch_bounds__(256) void k_score(const float* __restrict__ patch,
                                               const float* __restrict__ w_avg,
                                               const int* __restrict__ bnd,
                                               float* __restrict__ acc) {
    constexpr int CHUNKS = 32;
    constexpr int PPB = NP / CHUNKS;  // 128 patches per block
    constexpr int PPW = PPB / 4;      // 32 patches per wave
    int b = blockIdx.x / CHUNKS;
    int chunk = blockIdx.x % CHUNKS;
    __shared__ int bsh[NS + 1];
    int tid = threadIdx.x;
    if (tid <= NS) bsh[tid] = bnd[tid];
    __syncthreads();
    int wave = tid >> 6, lane = tid & 63;

    const float4* w4 = (const float4*)(w_avg + (size_t)b * DP);
    float4 w0 = w4[lane], w1 = w4[64 + lane], w2 = w4[128 + lane];
    float* accb = acc + (size_t)b * (NS + 1);

    int p0 = chunk * PPB + wave * PPW;

    // initial segment (once per wave): largest i with bsh[i] <= p0, dump=NS
    int cur, nxt;
    if (p0 < bsh[0]) {
        cur = NS; nxt = bsh[0];
    } else {
        int lo = 0, hi = NS;
        while (lo < hi) {
            int mid = (lo + hi + 1) >> 1;
            if (bsh[mid] <= p0) lo = mid; else hi = mid - 1;
        }
        cur = lo;
        nxt = (cur < NS) ? bsh[cur + 1] : NP;  // cur==NS: past-end dump forever
    }

    float4 r0 = {0, 0, 0, 0}, r1 = {0, 0, 0, 0}, r2 = {0, 0, 0, 0};

    for (int i = 0; i < PPW; ++i) {
        int p = p0 + i;
        if (p >= nxt) {  // wave-uniform: flush run, advance segment
            float s = r0.x * w0.x + r0.y * w0.y + r0.z * w0.z + r0.w * w0.w
                    + r1.x * w1.x + r1.y * w1.y + r1.z * w1.z + r1.w * w1.w
                    + r2.x * w2.x + r2.y * w2.y + r2.z * w2.z + r2.w * w2.w;
#pragma unroll
            for (int off = 32; off > 0; off >>= 1) s += __shfl_xor(s, off);
            if (lane == 0) atomicAdd(&accb[cur], s);
            r0 = {0, 0, 0, 0}; r1 = {0, 0, 0, 0}; r2 = {0, 0, 0, 0};
            cur = (cur == NS) ? 0 : cur + 1;      // crossed bsh[0] or bsh[cur+1]
            while (cur < NS && bsh[cur + 1] <= p) cur++;
            nxt = (cur < NS) ? bsh[cur + 1] : NP;
        }
        const float4* r4 = (const float4*)(patch + ((size_t)b * NP + p) * DP);
        float4 v0 = r4[lane], v1 = r4[64 + lane], v2 = r4[128 + lane];
        r0.x += v0.x; r0.y += v0.y; r0.z += v0.z; r0.w += v0.w;
        r1.x += v1.x; r1.y += v1.y; r1.z += v1.z; r1.w += v1.w;
        r2.x += v2.x; r2.y += v2.y; r2.z += v2.z; r2.w += v2.w;
    }
    // final flush
    {
        float s = r0.x * w0.x + r0.y * w0.y + r0.z * w0.z + r0.w * w0.w
                + r1.x * w1.x + r1.y * w1.y + r1.z * w1.z + r1.w * w1.w
                + r2.x * w2.x + r2.y * w2.y + r2.z * w2.z + r2.w * w2.w;
#pragma unroll
        for (int off = 32; off > 0; off >>= 1) s += __shfl_xor(s, off);
        if (lane == 0) atomicAdd(&accb[cur], s);
    }
}

// ---------------------------------------------------------------------------
// Kernel D: out[b,s] = sigmoid(acc[b,s]/cnt + bavg[b]) if cnt>0 else sigmoid(0)
// ---------------------------------------------------------------------------
__global__ __launch_bounds__(256) void k_out(const float* __restrict__ acc,
                                             const float* __restrict__ bavg,
                                             const int* __restrict__ bnd,
                                             float* __restrict__ out) {
    int i = blockIdx.x * 256 + threadIdx.x;  // 0 .. NB*NS-1
    if (i >= NB * NS) return;
    int b = i / NS, s = i % NS;
    int cnt = bnd[s + 1] - bnd[s];
    float v = 0.f;
    if (cnt > 0) v = acc[b * (NS + 1) + s] / (float)cnt + bavg[b];
    out[i] = 1.0f / (1.0f + expf(-v));
}

extern "C" void kernel_launch(void* const* d_in, const int* in_sizes, int n_in,
                              void* d_out, int out_size, void* d_ws, size_t ws_size,
                              hipStream_t stream) {
    const float* h_int = (const float*)d_in[0];
    const float* h_vc  = (const float*)d_in[1];
    const float* patch = (const float*)d_in[2];
    const int*   bnd   = (const int*)d_in[3];
    const float* qW    = (const float*)d_in[4];
    const float* qb    = (const float*)d_in[5];
    const float* kW    = (const float*)d_in[6];
    const float* kb    = (const float*)d_in[7];
    float* out = (float*)d_out;

    // workspace layout: [acc NB*(NS+1)] [w_avg NB*DP] [bavg NB] [q NB*NH*DH]
    float* acc   = (float*)d_ws;
    float* w_avg = acc + NB * (NS + 1);
    float* bavg  = w_avg + NB * DP;
    float* q     = bavg + NB;
    int nzero = NB * (NS + 1) + NB * DP + NB;  // acc + w_avg + bavg

    k_zero<<<(nzero + 255) / 256, 256, 0, stream>>>(acc, nzero);
    k_q<<<NB * NH, 256, 0, stream>>>(h_int, h_vc, qW, qb, q);
    k_wavg<<<NB * KSPLIT, 256, 0, stream>>>(q, kW, kb, w_avg, bavg);
    k_score<<<NB * 32, 256, 0, stream>>>(patch, w_avg, bnd, acc);
    k_out<<<(NB * NS + 255) / 256, 256, 0, stream>>>(acc, bavg, bnd, out);
}

// Round 3
// 132.569 us; speedup vs baseline: 1.4915x; 1.0455x over previous
//
#include <hip/hip_runtime.h>
#include <math.h>

#define NB 32
#define NP 4096
#define NS 128
#define DI 512
#define DV 512
#define DP 768
#define NH 4
#define DC 1024
#define DH 256

// ---------------------------------------------------------------------------
// Kernel 1 (fused): per block (b,h):
//   q[d]           = dot(h_concat[b,:], qW[h,d,:]) + qb[h,d]        (LDS only)
//   w_part[b,h,c]  = (1/H) * sum_d q[d] * kW[h,d,c]                 (owned slice)
//   bavg_part[b,h] = (1/H) * sum_d q[d] * kb[h,d]
// Also zeroes acc[] (kernel boundary orders this before k_score's atomics).
// grid = NB*NH = 128 blocks, 256 threads.
// ---------------------------------------------------------------------------
__global__ __launch_bounds__(256) void k_qw(const float* __restrict__ h_int,
                                            const float* __restrict__ h_vc,
                                            const float* __restrict__ qW,
                                            const float* __restrict__ qb,
                                            const float* __restrict__ kW,
                                            const float* __restrict__ kb,
                                            float* __restrict__ w_part,
                                            float* __restrict__ bavg_part,
                                            float* __restrict__ acc) {
    int b = blockIdx.x / NH, h = blockIdx.x % NH;
    int tid = threadIdx.x;

    // zero the k_score accumulator (4128 elements < 128*256 threads)
    int g = blockIdx.x * 256 + tid;
    if (g < NB * (NS + 1)) acc[g] = 0.f;

    __shared__ float hc[DC];
    __shared__ float qs[DH];
    for (int i = tid; i < DI; i += 256) hc[i] = h_int[b * DI + i];
    for (int i = tid; i < DV; i += 256) hc[DI + i] = h_vc[b * DV + i];
    __syncthreads();

    // phase 1: q[d=tid]
    const float* w = qW + (size_t)(h * DH + tid) * DC;
    float acc_q = qb[h * DH + tid];
#pragma unroll 8
    for (int c = 0; c < DC; c += 4) {
        float4 wv = *(const float4*)(w + c);
        acc_q += wv.x * hc[c] + wv.y * hc[c + 1] + wv.z * hc[c + 2] + wv.w * hc[c + 3];
    }
    qs[tid] = acc_q;
    __syncthreads();

    // phase 2: contract q against kW rows of this head (thread owns c, c+256, c+512)
    float a0 = 0.f, a1 = 0.f, a2 = 0.f;
    for (int i = 0; i < DH; ++i) {
        float qv = qs[i];
        const float* kr = kW + (size_t)(h * DH + i) * DP;
        a0 += qv * kr[tid];
        a1 += qv * kr[tid + 256];
        a2 += qv * kr[tid + 512];
    }
    const float inv_h = 1.0f / NH;
    float* wp = w_part + (size_t)(b * NH + h) * DP;
    wp[tid]       = a0 * inv_h;
    wp[tid + 256] = a1 * inv_h;
    wp[tid + 512] = a2 * inv_h;

    // bias partial: sum_d qs[d]*kb[h,d]
    float pb = qs[tid] * kb[h * DH + tid];
#pragma unroll
    for (int off = 32; off > 0; off >>= 1) pb += __shfl_xor(pb, off);
    __shared__ float red[4];
    int wave = tid >> 6, lane = tid & 63;
    if (lane == 0) red[wave] = pb;
    __syncthreads();
    if (tid == 0) bavg_part[b * NH + h] = (red[0] + red[1] + red[2] + red[3]) * inv_h;
}

// ---------------------------------------------------------------------------
// Kernel 2 (heavy, streaming): per segment-run, accumulate the VECTOR sum of
// patches in registers; dot+reduce+atomic only at segment crossings. 2-deep
// software prefetch (6 loads in flight/wave); segment advances monotonically.
// grid = NB*CHUNKS blocks (CHUNKS=64 -> 32 waves/CU), 256 threads.
// ---------------------------------------------------------------------------
__global__ __launch_bounds__(256) void k_score(const float* __restrict__ patch,
                                               const float* __restrict__ w_part,
                                               const int* __restrict__ bnd,
                                               float* __restrict__ acc) {
    constexpr int CHUNKS = 64;
    constexpr int PPB = NP / CHUNKS;  // 64 patches per block
    constexpr int PPW = PPB / 4;      // 16 patches per wave
    int b = blockIdx.x / CHUNKS;
    int chunk = blockIdx.x % CHUNKS;
    __shared__ int bsh[NS + 1];
    int tid = threadIdx.x;
    if (tid <= NS) bsh[tid] = bnd[tid];
    __syncthreads();
    int wave = tid >> 6, lane = tid & 63;

    // weights: sum the 4 per-head partials (L2-hot, 12 loads/lane)
    const float4* wp = (const float4*)(w_part + (size_t)b * NH * DP);
    float4 w0 = {0, 0, 0, 0}, w1 = {0, 0, 0, 0}, w2 = {0, 0, 0, 0};
#pragma unroll
    for (int h = 0; h < NH; ++h) {
        float4 t0 = wp[h * (DP / 4) + lane];
        float4 t1 = wp[h * (DP / 4) + 64 + lane];
        float4 t2 = wp[h * (DP / 4) + 128 + lane];
        w0.x += t0.x; w0.y += t0.y; w0.z += t0.z; w0.w += t0.w;
        w1.x += t1.x; w1.y += t1.y; w1.z += t1.z; w1.w += t1.w;
        w2.x += t2.x; w2.y += t2.y; w2.z += t2.z; w2.w += t2.w;
    }
    float* accb = acc + (size_t)b * (NS + 1);

    int p0 = chunk * PPB + wave * PPW;

    // initial segment (once per wave): largest i with bsh[i] <= p0; dump = NS
    int cur, nxt;
    if (p0 < bsh[0]) {
        cur = NS; nxt = bsh[0];
    } else {
        int lo = 0, hi = NS;
        while (lo < hi) {
            int mid = (lo + hi + 1) >> 1;
            if (bsh[mid] <= p0) lo = mid; else hi = mid - 1;
        }
        cur = lo;
        nxt = (cur < NS) ? bsh[cur + 1] : NP;
    }

    float4 r0 = {0, 0, 0, 0}, r1 = {0, 0, 0, 0}, r2 = {0, 0, 0, 0};

    const float4* row = (const float4*)(patch + ((size_t)b * NP + p0) * DP);
    float4 v0 = row[lane], v1 = row[64 + lane], v2 = row[128 + lane];

    for (int i = 0; i < PPW; ++i) {
        int p = p0 + i;
        // prefetch next row (clamped on last iter; issues before the branch)
        const float4* nrow = (i + 1 < PPW) ? row + (DP / 4) : row;
        float4 n0 = nrow[lane], n1 = nrow[64 + lane], n2 = nrow[128 + lane];

        if (p >= nxt) {  // wave-uniform: flush run, advance segment
            float s = r0.x * w0.x + r0.y * w0.y + r0.z * w0.z + r0.w * w0.w
                    + r1.x * w1.x + r1.y * w1.y + r1.z * w1.z + r1.w * w1.w
                    + r2.x * w2.x + r2.y * w2.y + r2.z * w2.z + r2.w * w2.w;
#pragma unroll
            for (int off = 32; off > 0; off >>= 1) s += __shfl_xor(s, off);
            if (lane == 0) atomicAdd(&accb[cur], s);
            r0 = {0, 0, 0, 0}; r1 = {0, 0, 0, 0}; r2 = {0, 0, 0, 0};
            cur = (cur == NS) ? 0 : cur + 1;
            while (cur < NS && bsh[cur + 1] <= p) cur++;
            nxt = (cur < NS) ? bsh[cur + 1] : NP;
        }
        r0.x += v0.x; r0.y += v0.y; r0.z += v0.z; r0.w += v0.w;
        r1.x += v1.x; r1.y += v1.y; r1.z += v1.z; r1.w += v1.w;
        r2.x += v2.x; r2.y += v2.y; r2.z += v2.z; r2.w += v2.w;
        v0 = n0; v1 = n1; v2 = n2; row = nrow;
    }
    // final flush
    {
        float s = r0.x * w0.x + r0.y * w0.y + r0.z * w0.z + r0.w * w0.w
                + r1.x * w1.x + r1.y * w1.y + r1.z * w1.z + r1.w * w1.w
                + r2.x * w2.x + r2.y * w2.y + r2.z * w2.z + r2.w * w2.w;
#pragma unroll
        for (int off = 32; off > 0; off >>= 1) s += __shfl_xor(s, off);
        if (lane == 0) atomicAdd(&accb[cur], s);
    }
}

// ---------------------------------------------------------------------------
// Kernel 3: out[b,s] = sigmoid(acc[b,s]/cnt + sum_h bavg_part[b,h]) , cnt>0
//           else sigmoid(0)
// ---------------------------------------------------------------------------
__global__ __launch_bounds__(256) void k_out(const float* __restrict__ acc,
                                             const float* __restrict__ bavg_part,
                                             const int* __restrict__ bnd,
                                             float* __restrict__ out) {
    int i = blockIdx.x * 256 + threadIdx.x;  // 0 .. NB*NS-1
    if (i >= NB * NS) return;
    int b = i / NS, s = i % NS;
    int cnt = bnd[s + 1] - bnd[s];
    float v = 0.f;
    if (cnt > 0) {
        float bb = bavg_part[b * NH] + bavg_part[b * NH + 1]
                 + bavg_part[b * NH + 2] + bavg_part[b * NH + 3];
        v = acc[b * (NS + 1) + s] / (float)cnt + bb;
    }
    out[i] = 1.0f / (1.0f + expf(-v));
}

extern "C" void kernel_launch(void* const* d_in, const int* in_sizes, int n_in,
                              void* d_out, int out_size, void* d_ws, size_t ws_size,
                              hipStream_t stream) {
    const float* h_int = (const float*)d_in[0];
    const float* h_vc  = (const float*)d_in[1];
    const float* patch = (const float*)d_in[2];
    const int*   bnd   = (const int*)d_in[3];
    const float* qW    = (const float*)d_in[4];
    const float* qb    = (const float*)d_in[5];
    const float* kW    = (const float*)d_in[6];
    const float* kb    = (const float*)d_in[7];
    float* out = (float*)d_out;

    // workspace: [acc NB*(NS+1)] [w_part NB*NH*DP] [bavg_part NB*NH]
    float* acc       = (float*)d_ws;
    float* w_part    = acc + NB * (NS + 1);
    float* bavg_part = w_part + NB * NH * DP;

    k_qw<<<NB * NH, 256, 0, stream>>>(h_int, h_vc, qW, qb, kW, kb,
                                      w_part, bavg_part, acc);
    k_score<<<NB * 64, 256, 0, stream>>>(patch, w_part, bnd, acc);
    k_out<<<(NB * NS + 255) / 256, 256, 0, stream>>>(acc, bavg_part, bnd, out);
}

// Round 5
// 110.781 us; speedup vs baseline: 1.7849x; 1.1967x over previous
//
#include <hip/hip_runtime.h>
#include <math.h>

#define NB 32
#define NP 4096
#define NS 128
#define DI 512
#define DV 512
#define DP 768
#define NH 4
#define DC 1024
#define DH 256

// clang native vector (required by __builtin_nontemporal_load; supports .xyzw)
typedef float f4 __attribute__((ext_vector_type(4)));

// ---------------------------------------------------------------------------
// Kernel 1 (fused): per block (b,h):
//   q[d]           = dot(h_concat[b,:], qW[h,d,:]) + qb[h,d]   (LDS only)
//   w_part[b,h,c]  = (1/H) * sum_d q[d] * kW[h,d,c]            (owned slice)
//   bavg_part[b,h] = (1/H) * sum_d q[d] * kb[h,d]
// Also zeroes acc[] (kernel boundary orders this before k_score's atomics).
// grid = NB*NH = 128 blocks, 256 threads.
// ---------------------------------------------------------------------------
__global__ __launch_bounds__(256) void k_qw(const float* __restrict__ h_int,
                                            const float* __restrict__ h_vc,
                                            const float* __restrict__ qW,
                                            const float* __restrict__ qb,
                                            const float* __restrict__ kW,
                                            const float* __restrict__ kb,
                                            float* __restrict__ w_part,
                                            float* __restrict__ bavg_part,
                                            float* __restrict__ acc) {
    int b = blockIdx.x / NH, h = blockIdx.x % NH;
    int tid = threadIdx.x;

    // zero the k_score accumulator (4128 elements < 128*256 threads)
    int g = blockIdx.x * 256 + tid;
    if (g < NB * (NS + 1)) acc[g] = 0.f;

    __shared__ float hc[DC];
    __shared__ float qs[DH];
    for (int i = tid; i < DI; i += 256) hc[i] = h_int[b * DI + i];
    for (int i = tid; i < DV; i += 256) hc[DI + i] = h_vc[b * DV + i];
    __syncthreads();

    // phase 1: q[d=tid]
    const float* w = qW + (size_t)(h * DH + tid) * DC;
    float acc_q = qb[h * DH + tid];
#pragma unroll 8
    for (int c = 0; c < DC; c += 4) {
        f4 wv = *(const f4*)(w + c);
        acc_q += wv.x * hc[c] + wv.y * hc[c + 1] + wv.z * hc[c + 2] + wv.w * hc[c + 3];
    }
    qs[tid] = acc_q;
    __syncthreads();

    // phase 2: contract q against kW rows of this head (thread owns c,c+256,c+512)
    // unroll 8 -> 24 independent loads in flight, kills the L2-latency serial chain
    float a0 = 0.f, a1 = 0.f, a2 = 0.f;
#pragma unroll 8
    for (int i = 0; i < DH; ++i) {
        float qv = qs[i];
        const float* kr = kW + (size_t)(h * DH + i) * DP;
        a0 += qv * kr[tid];
        a1 += qv * kr[tid + 256];
        a2 += qv * kr[tid + 512];
    }
    const float inv_h = 1.0f / NH;
    float* wp = w_part + (size_t)(b * NH + h) * DP;
    wp[tid]       = a0 * inv_h;
    wp[tid + 256] = a1 * inv_h;
    wp[tid + 512] = a2 * inv_h;

    // bias partial: sum_d qs[d]*kb[h,d]
    float pb = qs[tid] * kb[h * DH + tid];
#pragma unroll
    for (int off = 32; off > 0; off >>= 1) pb += __shfl_xor(pb, off);
    __shared__ float red[4];
    int wave = tid >> 6, lane = tid & 63;
    if (lane == 0) red[wave] = pb;
    __syncthreads();
    if (tid == 0) bavg_part[b * NH + h] = (red[0] + red[1] + red[2] + red[3]) * inv_h;
}

// ---------------------------------------------------------------------------
// Kernel 2 (heavy, streaming): register run-accumulation of patch-row vector
// sums; dot+reduce+atomic only at segment crossings (monotone advance).
// 2-row-deep software pipeline (6 KB in flight per wave), nontemporal loads
// (403 MB stream, zero reuse), PPW=32 rows per wave.
// grid = NB*CHUNKS (CHUNKS=32 -> 1024 blocks), 256 threads.
// ---------------------------------------------------------------------------
__global__ __launch_bounds__(256, 4) void k_score(const float* __restrict__ patch,
                                                  const float* __restrict__ w_part,
                                                  const int* __restrict__ bnd,
                                                  float* __restrict__ acc) {
    constexpr int CHUNKS = 32;
    constexpr int PPB = NP / CHUNKS;  // 128 patches per block
    constexpr int PPW = PPB / 4;      // 32 patches per wave
    constexpr int RS = DP / 4;        // row stride in f4 (192)
    int b = blockIdx.x / CHUNKS;
    int chunk = blockIdx.x % CHUNKS;
    __shared__ int bsh[NS + 1];
    int tid = threadIdx.x;
    if (tid <= NS) bsh[tid] = bnd[tid];
    __syncthreads();
    int wave = tid >> 6, lane = tid & 63;

    // weights: sum the 4 per-head partials (L2-hot)
    const f4* wp = (const f4*)(w_part + (size_t)b * NH * DP);
    f4 w0 = 0.f, w1 = 0.f, w2 = 0.f;
#pragma unroll
    for (int h = 0; h < NH; ++h) {
        w0 += wp[h * RS + lane];
        w1 += wp[h * RS + 64 + lane];
        w2 += wp[h * RS + 128 + lane];
    }
    float* accb = acc + (size_t)b * (NS + 1);

    int p0 = chunk * PPB + wave * PPW;

    // initial segment: largest i with bsh[i] <= p0; dump = NS
    int cur, nxt;
    if (p0 < bsh[0]) {
        cur = NS; nxt = bsh[0];
    } else {
        int lo = 0, hi = NS;
        while (lo < hi) {
            int mid = (lo + hi + 1) >> 1;
            if (bsh[mid] <= p0) lo = mid; else hi = mid - 1;
        }
        cur = lo;
        nxt = (cur < NS) ? bsh[cur + 1] : NP;
    }

    f4 r0 = 0.f, r1 = 0.f, r2 = 0.f;
    const f4* base = (const f4*)(patch + ((size_t)b * NP + p0) * DP);

#define LOADROW(dst0, dst1, dst2, i)                                          \
    {                                                                         \
        const f4* rp_ = base + (size_t)(i) * RS;                              \
        dst0 = __builtin_nontemporal_load(rp_ + lane);                        \
        dst1 = __builtin_nontemporal_load(rp_ + 64 + lane);                   \
        dst2 = __builtin_nontemporal_load(rp_ + 128 + lane);                  \
    }

#define PROCROW(s0, s1, s2, i)                                                \
    {                                                                         \
        int p_ = p0 + (i);                                                    \
        if (p_ >= nxt) { /* wave-uniform: flush run, advance segment */       \
            f4 sv = r0 * w0 + r1 * w1 + r2 * w2;                              \
            float s = sv.x + sv.y + sv.z + sv.w;                              \
            for (int off_ = 32; off_ > 0; off_ >>= 1) s += __shfl_xor(s, off_); \
            if (lane == 0) atomicAdd(&accb[cur], s);                          \
            r0 = 0.f; r1 = 0.f; r2 = 0.f;                                     \
            cur = (cur == NS) ? 0 : cur + 1;                                  \
            while (cur < NS && bsh[cur + 1] <= p_) cur++;                     \
            nxt = (cur < NS) ? bsh[cur + 1] : NP;                             \
        }                                                                     \
        r0 += s0; r1 += s1; r2 += s2;                                         \
    }

    f4 A0, A1, A2, B0, B1, B2, C0, C1, C2, D0, D1, D2;
    LOADROW(A0, A1, A2, 0)
    LOADROW(B0, B1, B2, 1)
#pragma unroll
    for (int g2 = 0; g2 < PPW - 2; g2 += 2) {
        LOADROW(C0, C1, C2, g2 + 2)
        LOADROW(D0, D1, D2, g2 + 3)
        PROCROW(A0, A1, A2, g2)
        PROCROW(B0, B1, B2, g2 + 1)
        A0 = C0; A1 = C1; A2 = C2;
        B0 = D0; B1 = D1; B2 = D2;
    }
    PROCROW(A0, A1, A2, PPW - 2)
    PROCROW(B0, B1, B2, PPW - 1)

    // final flush
    {
        f4 sv = r0 * w0 + r1 * w1 + r2 * w2;
        float s = sv.x + sv.y + sv.z + sv.w;
#pragma unroll
        for (int off = 32; off > 0; off >>= 1) s += __shfl_xor(s, off);
        if (lane == 0) atomicAdd(&accb[cur], s);
    }
#undef LOADROW
#undef PROCROW
}

// ---------------------------------------------------------------------------
// Kernel 3: out[b,s] = sigmoid(acc[b,s]/cnt + sum_h bavg_part[b,h]) if cnt>0
//           else sigmoid(0)
// ---------------------------------------------------------------------------
__global__ __launch_bounds__(256) void k_out(const float* __restrict__ acc,
                                             const float* __restrict__ bavg_part,
                                             const int* __restrict__ bnd,
                                             float* __restrict__ out) {
    int i = blockIdx.x * 256 + threadIdx.x;  // 0 .. NB*NS-1
    if (i >= NB * NS) return;
    int b = i / NS, s = i % NS;
    int cnt = bnd[s + 1] - bnd[s];
    float v = 0.f;
    if (cnt > 0) {
        float bb = bavg_part[b * NH] + bavg_part[b * NH + 1]
                 + bavg_part[b * NH + 2] + bavg_part[b * NH + 3];
        v = acc[b * (NS + 1) + s] / (float)cnt + bb;
    }
    out[i] = 1.0f / (1.0f + expf(-v));
}

extern "C" void kernel_launch(void* const* d_in, const int* in_sizes, int n_in,
                              void* d_out, int out_size, void* d_ws, size_t ws_size,
                              hipStream_t stream) {
    const float* h_int = (const float*)d_in[0];
    const float* h_vc  = (const float*)d_in[1];
    const float* patch = (const float*)d_in[2];
    const int*   bnd   = (const int*)d_in[3];
    const float* qW    = (const float*)d_in[4];
    const float* qb    = (const float*)d_in[5];
    const float* kW    = (const float*)d_in[6];
    const float* kb    = (const float*)d_in[7];
    float* out = (float*)d_out;

    // workspace: [acc NB*(NS+1)] [w_part NB*NH*DP] [bavg_part NB*NH]
    float* acc       = (float*)d_ws;
    float* w_part    = acc + NB * (NS + 1);
    float* bavg_part = w_part + NB * NH * DP;

    k_qw<<<NB * NH, 256, 0, stream>>>(h_int, h_vc, qW, qb, kW, kb,
                                      w_part, bavg_part, acc);
    k_score<<<NB * 32, 256, 0, stream>>>(patch, w_part, bnd, acc);
    k_out<<<(NB * NS + 255) / 256, 256, 0, stream>>>(acc, bavg_part, bnd, out);
}